// Round 1
// baseline (11.383 us; speedup 1.0000x reference)
//
#include <hip/hip_runtime.h>
#include <math.h>

// Problem constants (from reference): B=256, D=784, H=512
#define BSZ 256
#define DD  784
#define HH  512

__device__ __forceinline__ float sigmoidf_(float a) {
    // 1/(1+e^-a) via hw exp; rel err ~5e-7, far inside the 1.56e-2 threshold
    return 1.0f / (1.0f + __expf(-a));
}

// One block per output column d. Phase 1: reduce L0[d], L1[d] over H.
// Phase 2: 256 threads = 256 batch rows write out[:, d].
__global__ __launch_bounds__(256) void nade_kernel(
    const float* __restrict__ x,    // (B, D)
    const float* __restrict__ V,    // (D, H)
    const float* __restrict__ bvec, // (D,)
    const float* __restrict__ W,    // (H, D)
    const float* __restrict__ c,    // (1, H)
    float* __restrict__ out)        // (B, D)
{
    const int d = blockIdx.x;
    const int t = threadIdx.x;

    // ---- Phase 1: partial sums over H (2 h's per thread) ----
    float p0 = 0.f, q0 = 0.f, p1 = 0.f, q1 = 0.f;
    #pragma unroll
    for (int i = 0; i < 2; ++i) {
        const int h = t + i * 256;
        const float ch = c[h];
        const float s0 = sigmoidf_(ch);
        const float v  = V[d * HH + h];
        p0 += s0 * v;
        q0 += s0;
        if (d >= 1) {
            const float w  = W[h * DD + (d - 1)];
            const float s1 = sigmoidf_(w + ch);
            const float ds = s1 - s0;
            p1 += ds * v;
            q1 += ds;
        }
    }

    // wave-64 butterfly-free down-reduce
    #pragma unroll
    for (int off = 32; off > 0; off >>= 1) {
        p0 += __shfl_down(p0, off);
        q0 += __shfl_down(q0, off);
        p1 += __shfl_down(p1, off);
        q1 += __shfl_down(q1, off);
    }

    __shared__ float red[4][4];
    __shared__ float Lsh[2];
    const int wave = t >> 6;
    if ((t & 63) == 0) {
        red[wave][0] = p0; red[wave][1] = q0;
        red[wave][2] = p1; red[wave][3] = q1;
    }
    __syncthreads();
    if (t == 0) {
        float P0 = 0.f, Q0 = 0.f, P1 = 0.f, Q1 = 0.f;
        #pragma unroll
        for (int wv = 0; wv < 4; ++wv) {
            P0 += red[wv][0]; Q0 += red[wv][1];
            P1 += red[wv][2]; Q1 += red[wv][3];
        }
        const float bd = bvec[d];
        Lsh[0] = P0 + bd * Q0;   // L0[d]
        Lsh[1] = P1 + bd * Q1;   // L1[d]
    }
    __syncthreads();
    const float L0 = Lsh[0];
    const float L1 = Lsh[1];

    // ---- Phase 2: thread t = batch row ----
    const float xv = (d >= 1) ? x[t * DD + (d - 1)] : 0.0f;
    out[t * DD + d] = sigmoidf_(L0 + xv * L1);
}

extern "C" void kernel_launch(void* const* d_in, const int* in_sizes, int n_in,
                              void* d_out, int out_size, void* d_ws, size_t ws_size,
                              hipStream_t stream) {
    const float* x    = (const float*)d_in[0]; // (256, 784)
    const float* V    = (const float*)d_in[1]; // (784, 512)
    const float* bvec = (const float*)d_in[2]; // (784,)
    const float* W    = (const float*)d_in[3]; // (512, 784)
    const float* c    = (const float*)d_in[4]; // (1, 512)
    float* out = (float*)d_out;                // (256, 784)

    nade_kernel<<<DD, BSZ, 0, stream>>>(x, V, bvec, W, c, out);
}